// Round 8
// baseline (7231.264 us; speedup 1.0000x reference)
//
#include <hip/hip_runtime.h>
#include <hip/hip_cooperative_groups.h>
#include <cstdint>
#include <cmath>

namespace cg = cooperative_groups;

#define MASKV -9.0e20f

// ---------------- Threefry-2x32 (JAX-compatible) ----------------
__host__ __device__ inline void tf2x32(uint32_t k0, uint32_t k1, uint32_t& x0, uint32_t& x1){
  uint32_t ks2 = k0 ^ k1 ^ 0x1BD11BDAu;
  x0 += k0; x1 += k1;
#define TFR(r) { x0 += x1; x1 = (x1<<(r))|(x1>>(32-(r))); x1 ^= x0; }
  TFR(13) TFR(15) TFR(26) TFR(6)
  x0 += k1;  x1 += ks2 + 1u;
  TFR(17) TFR(29) TFR(16) TFR(24)
  x0 += ks2; x1 += k0 + 2u;
  TFR(13) TFR(15) TFR(26) TFR(6)
  x0 += k0;  x1 += k1 + 3u;
  TFR(17) TFR(29) TFR(16) TFR(24)
  x0 += k1;  x1 += ks2 + 4u;
  TFR(13) TFR(15) TFR(26) TFR(6)
  x0 += ks2; x1 += k0 + 5u;
#undef TFR
}

__device__ inline uint32_t rbits32(uint32_t k0, uint32_t k1, uint32_t idx){
  uint32_t x0 = 0u, x1 = idx;
  tf2x32(k0, k1, x0, x1);
  return x0 ^ x1;
}

__device__ inline float u01_from_bits(uint32_t bits){
  union { uint32_t u; float f; } c;
  c.u = (bits >> 9) | 0x3f800000u;
  return c.f - 1.0f;
}

__device__ inline float erfinv_f(float x){
  float w = -log1pf(-x*x);
  float p;
  if (w < 5.0f){
    w -= 2.5f;
    p = 2.81022636e-08f;
    p = fmaf(p, w, 3.43273939e-07f);
    p = fmaf(p, w, -3.5233877e-06f);
    p = fmaf(p, w, -4.39150654e-06f);
    p = fmaf(p, w, 0.00021858087f);
    p = fmaf(p, w, -0.00125372503f);
    p = fmaf(p, w, -0.00417768164f);
    p = fmaf(p, w, 0.246640727f);
    p = fmaf(p, w, 1.50140941f);
  } else {
    w = sqrtf(w) - 3.0f;
    p = -0.000200214257f;
    p = fmaf(p, w, 0.000100950558f);
    p = fmaf(p, w, 0.00134934322f);
    p = fmaf(p, w, -0.00367342844f);
    p = fmaf(p, w, 0.00573950773f);
    p = fmaf(p, w, -0.0076224613f);
    p = fmaf(p, w, 0.00943887047f);
    p = fmaf(p, w, 1.00167406f);
    p = fmaf(p, w, 2.83297682f);
  }
  return p * x;
}

__device__ inline float jax_normal(uint32_t k0, uint32_t k1, uint32_t idx){
  float f = u01_from_bits(rbits32(k0, k1, idx));
  float v = fmaf(f, 2.0f, -0.99999994f);
  v = fmaxf(v, -0.99999994f);
  return 1.41421356f * erfinv_f(v);
}

__device__ inline float jax_gumbel(uint32_t k0, uint32_t k1, uint32_t idx){
  float f = u01_from_bits(rbits32(k0, k1, idx));
  f = f + 1.17549435e-38f;
  f = fmaxf(f, 1.17549435e-38f);
  return -logf(-logf(f));
}

// ---------------- small tiled SGEMM (64x64 tile, 4x4 microtile) ----------------
template<int ACT>
__global__ __launch_bounds__(256) void gemm_k(
    const float* __restrict__ A, int lda,
    const long* __restrict__ atab, int anblk,
    const float* __restrict__ W, const float* __restrict__ bias,
    float* __restrict__ C, int K, int N,
    long c_base, int c_rdiv, long c_ostride, long c_istride)
{
  __shared__ float As[16][64];
  __shared__ float Ws[16][64];
  int tid = threadIdx.x;
  int c0 = blockIdx.x * 64;
  int r0 = blockIdx.y * 64;
  int lr = tid >> 2;
  int lk = (tid & 3) << 2;
  int wk = tid >> 4;
  int wc = (tid & 15) << 2;
  int tx = tid & 15;
  int ty = tid >> 4;
  long aoff0 = 0, aoff1 = 0;
  if (atab){
    const long* t = atab + (long)(r0 + lr) * anblk;
    aoff0 = t[0];
    if (anblk == 2) aoff1 = t[1];
  } else {
    aoff0 = (long)(r0 + lr) * lda;
  }
  float acc[4][4];
#pragma unroll
  for (int i = 0; i < 4; i++)
#pragma unroll
    for (int j = 0; j < 4; j++) acc[i][j] = 0.f;

  for (int k0 = 0; k0 < K; k0 += 16){
    int ka = k0 + lk;
    long ab = (atab && anblk == 2 && ka >= 512) ? (aoff1 + (ka - 512)) : (aoff0 + ka);
    float4 av = *(const float4*)(A + ab);
    As[lk + 0][lr] = av.x;
    As[lk + 1][lr] = av.y;
    As[lk + 2][lr] = av.z;
    As[lk + 3][lr] = av.w;
    float4 wv = *(const float4*)(W + (long)(k0 + wk) * N + (c0 + wc));
    *(float4*)&Ws[wk][wc] = wv;
    __syncthreads();
#pragma unroll
    for (int kk = 0; kk < 16; kk++){
      float4 a4 = *(const float4*)&As[kk][ty << 2];
      float4 w4 = *(const float4*)&Ws[kk][tx << 2];
      float aa[4] = {a4.x, a4.y, a4.z, a4.w};
      float ww[4] = {w4.x, w4.y, w4.z, w4.w};
#pragma unroll
      for (int i = 0; i < 4; i++)
#pragma unroll
        for (int j = 0; j < 4; j++)
          acc[i][j] = fmaf(aa[i], ww[j], acc[i][j]);
    }
    __syncthreads();
  }
  float4 bv = *(const float4*)(bias + c0 + (tx << 2));
  float bb[4] = {bv.x, bv.y, bv.z, bv.w};
#pragma unroll
  for (int i = 0; i < 4; i++){
    int r = r0 + (ty << 2) + i;
    long off = c_base + (long)(r / c_rdiv) * c_ostride + (long)(r % c_rdiv) * c_istride
               + c0 + (tx << 2);
    float4 v;
    float o0 = acc[i][0] + bb[0], o1 = acc[i][1] + bb[1];
    float o2 = acc[i][2] + bb[2], o3 = acc[i][3] + bb[3];
    if (ACT){ o0 = fmaxf(o0, 0.f); o1 = fmaxf(o1, 0.f); o2 = fmaxf(o2, 0.f); o3 = fmaxf(o3, 0.f); }
    v.x = o0; v.y = o1; v.z = o2; v.w = o3;
    *(float4*)(C + off) = v;
  }
}

// ---------------- 256x128-tile fused policy GEMM (measured-best: 216us, VGPR 52) ----------------
__global__ __launch_bounds__(512, 4) void gemm128f_k(
    const float* __restrict__ Y,
    const long* __restrict__ atab,
    const float* __restrict__ b1,
    const float* __restrict__ W2, const float* __restrict__ b2,
    const float* __restrict__ w3,
    const int* __restrict__ scat, float* __restrict__ logits)
{
  __shared__ float As[16][260];
  __shared__ float Ws[16][132];
  int tid = threadIdx.x;
  int c0 = blockIdx.x * 128;
  int r0 = blockIdx.y * 256;
  int tx = tid & 15, ty = tid >> 4;   // ty in [0,32): 8 rows each
  int rA = tid >> 1;                  // [0,256): staged A-row
  int kh = (tid & 1) << 3;            // 0 or 8
  long a0r = atab[(long)(r0 + rA) * 2];
  long a1r = atab[(long)(r0 + rA) * 2 + 1];
  int wk = tid >> 5;                  // [0,16)
  int wc = (tid & 31) << 2;           // [0,128)
  float acc[8][8];
#pragma unroll
  for (int i = 0; i < 8; i++)
#pragma unroll
    for (int j = 0; j < 8; j++) acc[i][j] = 0.f;

  for (int k0 = 0; k0 < 512; k0 += 16){
    float4 p0 = *(const float4*)(Y + a0r + k0 + kh);
    float4 p1 = *(const float4*)(Y + a0r + k0 + kh + 4);
    float4 q0 = *(const float4*)(Y + a1r + k0 + kh);
    float4 q1 = *(const float4*)(Y + a1r + k0 + kh + 4);
    float4 bv0 = *(const float4*)(b1 + k0 + kh);
    float4 bv1 = *(const float4*)(b1 + k0 + kh + 4);
    As[kh + 0][rA] = fmaxf(p0.x + q0.x + bv0.x, 0.f);
    As[kh + 1][rA] = fmaxf(p0.y + q0.y + bv0.y, 0.f);
    As[kh + 2][rA] = fmaxf(p0.z + q0.z + bv0.z, 0.f);
    As[kh + 3][rA] = fmaxf(p0.w + q0.w + bv0.w, 0.f);
    As[kh + 4][rA] = fmaxf(p1.x + q1.x + bv1.x, 0.f);
    As[kh + 5][rA] = fmaxf(p1.y + q1.y + bv1.y, 0.f);
    As[kh + 6][rA] = fmaxf(p1.z + q1.z + bv1.z, 0.f);
    As[kh + 7][rA] = fmaxf(p1.w + q1.w + bv1.w, 0.f);
    *(float4*)&Ws[wk][wc] = *(const float4*)(W2 + (long)(k0 + wk) * 512 + (c0 + wc));
    __syncthreads();
#pragma unroll
    for (int kk = 0; kk < 16; kk++){
      float a8[8], w8[8];
      *(float4*)&a8[0] = *(const float4*)&As[kk][ty << 3];
      *(float4*)&a8[4] = *(const float4*)&As[kk][(ty << 3) + 4];
      *(float4*)&w8[0] = *(const float4*)&Ws[kk][tx << 2];
      *(float4*)&w8[4] = *(const float4*)&Ws[kk][(tx << 2) + 64];
#pragma unroll
      for (int i = 0; i < 8; i++)
#pragma unroll
        for (int j = 0; j < 8; j++)
          acc[i][j] = fmaf(a8[i], w8[j], acc[i][j]);
    }
    __syncthreads();
  }
  float bb[8], w3v[8];
  *(float4*)&bb[0]  = *(const float4*)(b2 + c0 + (tx << 2));
  *(float4*)&bb[4]  = *(const float4*)(b2 + c0 + (tx << 2) + 64);
  *(float4*)&w3v[0] = *(const float4*)(w3 + c0 + (tx << 2));
  *(float4*)&w3v[4] = *(const float4*)(w3 + c0 + (tx << 2) + 64);
#pragma unroll
  for (int i = 0; i < 8; i++){
    float p = 0.f;
#pragma unroll
    for (int j = 0; j < 8; j++)
      p = fmaf(fmaxf(acc[i][j] + bb[j], 0.f), w3v[j], p);
    for (int m = 1; m < 16; m <<= 1) p += __shfl_xor(p, m);
    if (tx == 0){
      int rr = (ty << 3) + i;
      atomicAdd(logits + scat[r0 + rr], p);
    }
  }
}

// ---------------- cooperative: gemm64f phase -> grid.sync -> sample phase ----------------
// Phase bodies are verbatim copies of the round-7 gemm64f_k / sample_k (bitwise-identical
// outputs); grid.sync() replaces the inter-kernel launch gap.
__global__ __launch_bounds__(256) void gs_k(
    const float* __restrict__ Y,
    const float* __restrict__ b1, const float* __restrict__ W2,
    const float* __restrict__ b2, const float* __restrict__ w3,
    float* __restrict__ logits, int nrb,
    int* __restrict__ active, int* __restrict__ actions,
    float* __restrict__ lp, float* __restrict__ ent,
    int it, int A, uint32_t gk0, uint32_t gk1, float log_opt,
    long* __restrict__ tab_loop, int* __restrict__ scat_loop,
    long* __restrict__ tab_pair, const float* __restrict__ pol_b3)
{
  __shared__ float As[16][64];
  __shared__ float Ws[16][64];
  __shared__ float rmax[4], rS[4], rT[4], rG[4];
  __shared__ int rGi[4];
  __shared__ int ss0, ss1;
  cg::grid_group grid = cg::this_grid();
  int bx = blockIdx.x;
  int tid = threadIdx.x;

  // ---- phase 1: gemm64f (blocks [0, nrb*8)) ----
  if (bx < nrb * 8){
    int c0 = (bx & 7) << 6;
    int r0 = (bx >> 3) << 6;
    int lr = tid >> 2;
    int lk = (tid & 3) << 2;
    int wk = tid >> 4;
    int wc = (tid & 15) << 2;
    int tx = tid & 15;
    int ty = tid >> 4;
    long a0 = tab_loop[(long)(r0 + lr) * 2];
    long a1 = tab_loop[(long)(r0 + lr) * 2 + 1];
    float acc[4][4];
#pragma unroll
    for (int i = 0; i < 4; i++)
#pragma unroll
      for (int j = 0; j < 4; j++) acc[i][j] = 0.f;

    for (int k0 = 0; k0 < 512; k0 += 16){
      int ka = k0 + lk;
      float4 p = *(const float4*)(Y + a0 + ka);
      float4 q = *(const float4*)(Y + a1 + ka);
      float4 bb = *(const float4*)(b1 + ka);
      As[lk + 0][lr] = fmaxf(p.x + q.x + bb.x, 0.f);
      As[lk + 1][lr] = fmaxf(p.y + q.y + bb.y, 0.f);
      As[lk + 2][lr] = fmaxf(p.z + q.z + bb.z, 0.f);
      As[lk + 3][lr] = fmaxf(p.w + q.w + bb.w, 0.f);
      *(float4*)&Ws[wk][wc] = *(const float4*)(W2 + (long)(k0 + wk) * 512 + (c0 + wc));
      __syncthreads();
#pragma unroll
      for (int kk = 0; kk < 16; kk++){
        float4 a4 = *(const float4*)&As[kk][ty << 2];
        float4 w4 = *(const float4*)&Ws[kk][tx << 2];
        float aa[4] = {a4.x, a4.y, a4.z, a4.w};
        float ww[4] = {w4.x, w4.y, w4.z, w4.w};
#pragma unroll
        for (int i = 0; i < 4; i++)
#pragma unroll
          for (int j = 0; j < 4; j++)
            acc[i][j] = fmaf(aa[i], ww[j], acc[i][j]);
      }
      __syncthreads();
    }
    float bb4[4], w34[4];
    *(float4*)&bb4[0] = *(const float4*)(b2 + c0 + (tx << 2));
    *(float4*)&w34[0] = *(const float4*)(w3 + c0 + (tx << 2));
#pragma unroll
    for (int i = 0; i < 4; i++){
      float p = 0.f;
#pragma unroll
      for (int j = 0; j < 4; j++)
        p = fmaf(fmaxf(acc[i][j] + bb4[j], 0.f), w34[j], p);
      for (int m = 1; m < 16; m <<= 1) p += __shfl_xor(p, m);
      if (tx == 0){
        int r = r0 + (ty << 2) + i;
        atomicAdd(logits + scat_loop[r], p);
      }
    }
  }
  grid.sync();

  // ---- phase 2: sample (blocks [0,128)) ----
  if (bx < 128){
    int b = bx;
    int lane = tid & 63, wid = tid >> 6;
    float* Lg = logits + (long)b * 900;

    // pass 1: max
    float v = -3.4e38f;
    for (int j = tid; j < 900; j += 256) v = fmaxf(v, Lg[j]);
#pragma unroll
    for (int m = 32; m; m >>= 1) v = fmaxf(v, __shfl_xor(v, m));
    if (lane == 0) rmax[wid] = v;
    __syncthreads();
    float mx = fmaxf(fmaxf(rmax[0], rmax[1]), fmaxf(rmax[2], rmax[3]));

    // pass 2: S = sum exp(l-m); T = sum e*(l-m) over unmasked
    float s = 0.f, t = 0.f;
    for (int j = tid; j < 900; j += 256){
      float l = Lg[j];
      float d = l - mx;
      float e = expf(d);
      s += e;
      if (l > MASKV) t = fmaf(e, d, t);
    }
#pragma unroll
    for (int m = 32; m; m >>= 1){ s += __shfl_xor(s, m); t += __shfl_xor(t, m); }
    if (lane == 0){ rS[wid] = s; rT[wid] = t; }

    // pass 3: gumbel argmax (earliest index wins on ties)
    float bv = -3.4e38f; int bi = 0;
    for (int j = tid; j < 900; j += 256){
      float g = jax_gumbel(gk0, gk1, (uint32_t)(b * 900 + j));
      float val = Lg[j] + g;
      if (val > bv){ bv = val; bi = j; }
    }
#pragma unroll
    for (int m = 32; m; m >>= 1){
      float ov = __shfl_xor(bv, m); int oi = __shfl_xor(bi, m);
      if (ov > bv || (ov == bv && oi < bi)){ bv = ov; bi = oi; }
    }
    if (lane == 0){ rG[wid] = bv; rGi[wid] = bi; }
    __syncthreads();

    if (tid == 0){
      float S = (rS[0] + rS[1]) + (rS[2] + rS[3]);
      float T = (rT[0] + rT[1]) + (rT[2] + rT[3]);
      ent[b] += -(T / S - logf(S)) / log_opt;
      float gb = rG[0]; int gi = rGi[0];
      for (int w = 1; w < 4; w++){
        if (rG[w] > gb || (rG[w] == gb && rGi[w] < gi)){ gb = rG[w]; gi = rGi[w]; }
      }
      int sf = gi;
      int s0 = sf / 30, s1 = sf % 30;
      ss0 = s0; ss1 = s1;
      actions[(b * 15 + it) * 2] = s0;
      actions[(b * 15 + it) * 2 + 1] = s1;
      lp[b * 15 + it] = Lg[sf] - mx - logf(S);
      tab_pair[b * 2]     = ((long)(b * 31 + s0)) * 512;
      tab_pair[b * 2 + 1] = ((long)(b * 31 + s1)) * 512;
    }
    __syncthreads();
    int s0 = ss0, s1 = ss1;
    if (tid < 30){
      Lg[s0 * 30 + tid] = MASKV;
      Lg[s1 * 30 + tid] = MASKV;
      Lg[tid * 30 + s0] = MASKV;
      Lg[tid * 30 + s1] = MASKV;
    }
    if (tid == 0){
      float b3v = pol_b3[0];
      int buf[16]; int c = 0;
      for (int k = 0; k < A; k++){
        int a = active[b * 16 + k];
        if (a != s0 && a != s1) buf[c++] = a;
      }
      int nt2 = 16 + it;
      buf[c++] = nt2;
      for (int k = 0; k < c; k++) active[b * 16 + k] = buf[k];
      int na2 = c - 1;
      for (int j = 0; j < na2; j++){
        int q = buf[j];
        int r1 = j * 128 + b;
        tab_loop[r1 * 2]     = ((long)(b * 31 + nt2)) * 1024;
        tab_loop[r1 * 2 + 1] = ((long)(b * 31 + q)) * 1024 + 512;
        int sc1 = b * 900 + nt2 * 30 + q;
        scat_loop[r1] = sc1;
        logits[sc1] = b3v;
        int r2 = (na2 + j) * 128 + b;
        tab_loop[r2 * 2]     = ((long)(b * 31 + q)) * 1024;
        tab_loop[r2 * 2 + 1] = ((long)(b * 31 + nt2)) * 1024 + 512;
        int sc2 = b * 900 + q * 30 + nt2;
        scat_loop[r2] = sc2;
        logits[sc2] = b3v;
      }
    }
  }
}

// ---------------- cooperative: enc chain pairmv -> mvrelu -> lay3z -> yrow ----------------
// 512 blocks x 256 threads; per-phase per-thread code verbatim from round-7 kernels.
__global__ __launch_bounds__(256) void encchain_k(
    float* __restrict__ u, const long* __restrict__ tab_pair,
    const float* __restrict__ w1e, const float* __restrict__ b1e,
    const float* __restrict__ w2e, const float* __restrict__ b2e,
    const float* __restrict__ w3e, const float* __restrict__ b3e,
    const float* __restrict__ W1cat, float* __restrict__ z_all,
    float* __restrict__ Y, int it, uint32_t nk0, uint32_t nk1,
    float* __restrict__ h1, float* __restrict__ h2)
{
  __shared__ float s[1024];
  cg::grid_group grid = cg::this_grid();
  int bx = blockIdx.x;
  int tid = threadIdx.x;

  // ---- phase 1: pairmv (blocks [0,256)) ----
  if (bx < 256){
    int b = bx & 127, xg = bx >> 7;
    int c = xg * 256 + tid;
    long t0 = tab_pair[b * 2], t1 = tab_pair[b * 2 + 1];
    s[tid]       = u[t0 + tid];
    s[tid + 256] = u[t0 + tid + 256];
    s[tid + 512] = u[t1 + tid];
    s[tid + 768] = u[t1 + tid + 256];
    __syncthreads();
    float a0 = 0.f, a1 = 0.f, a2 = 0.f, a3 = 0.f;
#pragma unroll 8
    for (int k = 0; k < 1024; k += 4){
      a0 = fmaf(s[k],     w1e[(long)k * 512 + c],       a0);
      a1 = fmaf(s[k + 1], w1e[(long)(k + 1) * 512 + c], a1);
      a2 = fmaf(s[k + 2], w1e[(long)(k + 2) * 512 + c], a2);
      a3 = fmaf(s[k + 3], w1e[(long)(k + 3) * 512 + c], a3);
    }
    float v = ((a0 + a1) + (a2 + a3)) + b1e[c];
    h1[(long)b * 512 + c] = fmaxf(v, 0.f);
  }
  grid.sync();

  // ---- phase 2: mvrelu h1 -> h2 (blocks [0,256)) ----
  if (bx < 256){
    int b = bx & 127, xg = bx >> 7;
    int c = xg * 256 + tid;
    const float* sr = h1 + (long)b * 512;
    s[tid] = sr[tid];
    s[tid + 256] = sr[tid + 256];
    __syncthreads();
    float a0 = 0.f, a1 = 0.f, a2 = 0.f, a3 = 0.f;
#pragma unroll 8
    for (int k = 0; k < 512; k += 4){
      a0 = fmaf(s[k],     w2e[(long)k * 512 + c],       a0);
      a1 = fmaf(s[k + 1], w2e[(long)(k + 1) * 512 + c], a1);
      a2 = fmaf(s[k + 2], w2e[(long)(k + 2) * 512 + c], a2);
      a3 = fmaf(s[k + 3], w2e[(long)(k + 3) * 512 + c], a3);
    }
    float v = ((a0 + a1) + (a2 + a3)) + b2e[c];
    h2[(long)b * 512 + c] = fmaxf(v, 0.f);
  }
  grid.sync();

  // ---- phase 3: lay3z h2 -> z_all, u (blocks [0,256)) ----
  if (bx < 256){
    int b = bx & 127, xg = bx >> 7;
    int c = xg * 256 + tid;
    const float* sr = h2 + (long)b * 512;
    s[tid] = sr[tid];
    s[tid + 256] = sr[tid + 256];
    __syncthreads();
    float a0 = 0.f, a1 = 0.f, a2 = 0.f, a3 = 0.f;
#pragma unroll 8
    for (int k = 0; k < 512; k += 4){
      a0 = fmaf(s[k],     w3e[(long)k * 512 + c],       a0);
      a1 = fmaf(s[k + 1], w3e[(long)(k + 1) * 512 + c], a1);
      a2 = fmaf(s[k + 2], w3e[(long)(k + 2) * 512 + c], a2);
      a3 = fmaf(s[k + 3], w3e[(long)(k + 3) * 512 + c], a3);
    }
    float v = ((a0 + a1) + (a2 + a3)) + b3e[c];
    z_all[(long)it * 65536 + (long)b * 512 + c] = v;
    float nv = jax_normal(nk0, nk1, (uint32_t)(b * 512 + c));
    u[((long)(b * 31 + 16 + it)) * 512 + c] = v + 0.01f * nv;
  }
  grid.sync();

  // ---- phase 4: yrow (all 512 blocks), skipped last iteration ----
  if (it < 14){
    int b = bx & 127, xg = bx >> 7;   // xg in [0,4)
    int c = xg * 256 + tid;
    const float* sr = u + ((long)(b * 31 + 16 + it)) * 512;
    s[tid] = sr[tid];
    s[tid + 256] = sr[tid + 256];
    __syncthreads();
    float a0 = 0.f, a1 = 0.f, a2 = 0.f, a3 = 0.f;
#pragma unroll 8
    for (int k = 0; k < 512; k += 4){
      a0 = fmaf(s[k],     W1cat[(long)k * 1024 + c],       a0);
      a1 = fmaf(s[k + 1], W1cat[(long)(k + 1) * 1024 + c], a1);
      a2 = fmaf(s[k + 2], W1cat[(long)(k + 2) * 1024 + c], a2);
      a3 = fmaf(s[k + 3], W1cat[(long)(k + 3) * 1024 + c], a3);
    }
    Y[((long)(b * 31 + 16 + it)) * 1024 + c] = (a0 + a1) + (a2 + a3);
  }
}

// ---------------- cooperative: reverse chain mvrelu -> mvrelu -> rev3 ----------------
__global__ __launch_bounds__(256) void revchain_k(
    float* __restrict__ dmat,
    const float* __restrict__ w1d, const float* __restrict__ b1d,
    const float* __restrict__ w2d, const float* __restrict__ b2d,
    const float* __restrict__ w3d, const float* __restrict__ b3d,
    const int* __restrict__ actions, int it,
    float* __restrict__ h1, float* __restrict__ h2)
{
  __shared__ float s[512];
  cg::grid_group grid = cg::this_grid();
  int bx = blockIdx.x;
  int tid = threadIdx.x;
  int tok = 30 - it;

  // ---- phase 1: mvrelu dmat[tok] -> h1 (blocks [0,256)) ----
  if (bx < 256){
    int b = bx & 127, xg = bx >> 7;
    int c = xg * 256 + tid;
    const float* sr = dmat + (long)tok * 512 + (long)b * 15872;
    s[tid] = sr[tid];
    s[tid + 256] = sr[tid + 256];
    __syncthreads();
    float a0 = 0.f, a1 = 0.f, a2 = 0.f, a3 = 0.f;
#pragma unroll 8
    for (int k = 0; k < 512; k += 4){
      a0 = fmaf(s[k],     w1d[(long)k * 512 + c],       a0);
      a1 = fmaf(s[k + 1], w1d[(long)(k + 1) * 512 + c], a1);
      a2 = fmaf(s[k + 2], w1d[(long)(k + 2) * 512 + c], a2);
      a3 = fmaf(s[k + 3], w1d[(long)(k + 3) * 512 + c], a3);
    }
    float v = ((a0 + a1) + (a2 + a3)) + b1d[c];
    h1[(long)b * 512 + c] = fmaxf(v, 0.f);
  }
  grid.sync();

  // ---- phase 2: mvrelu h1 -> h2 (blocks [0,256)) ----
  if (bx < 256){
    int b = bx & 127, xg = bx >> 7;
    int c = xg * 256 + tid;
    const float* sr = h1 + (long)b * 512;
    s[tid] = sr[tid];
    s[tid + 256] = sr[tid + 256];
    __syncthreads();
    float a0 = 0.f, a1 = 0.f, a2 = 0.f, a3 = 0.f;
#pragma unroll 8
    for (int k = 0; k < 512; k += 4){
      a0 = fmaf(s[k],     w2d[(long)k * 512 + c],       a0);
      a1 = fmaf(s[k + 1], w2d[(long)(k + 1) * 512 + c], a1);
      a2 = fmaf(s[k + 2], w2d[(long)(k + 2) * 512 + c], a2);
      a3 = fmaf(s[k + 3], w2d[(long)(k + 3) * 512 + c], a3);
    }
    float v = ((a0 + a1) + (a2 + a3)) + b2d[c];
    h2[(long)b * 512 + c] = fmaxf(v, 0.f);
  }
  grid.sync();

  // ---- phase 3: rev3 (all 512 blocks) ----
  {
    int b = bx & 127, xg = bx >> 7;   // xg in [0,4)
    int p = xg * 256 + tid;
    const float* sr = h2 + (long)b * 512;
    s[tid] = sr[tid];
    s[tid + 256] = sr[tid + 256];
    __syncthreads();
    float a0 = 0.f, a1 = 0.f, a2 = 0.f, a3 = 0.f;
#pragma unroll 8
    for (int k = 0; k < 512; k += 4){
      a0 = fmaf(s[k],     w3d[(long)k * 1024 + p],       a0);
      a1 = fmaf(s[k + 1], w3d[(long)(k + 1) * 1024 + p], a1);
      a2 = fmaf(s[k + 2], w3d[(long)(k + 2) * 1024 + p], a2);
      a3 = fmaf(s[k + 3], w3d[(long)(k + 3) * 1024 + p], a3);
    }
    float v = ((a0 + a1) + (a2 + a3)) + b3d[p];
    int fit = 14 - it;
    int s0 = actions[(b * 15 + fit) * 2];
    int s1 = actions[(b * 15 + fit) * 2 + 1];
    int node = (p < 512) ? s0 : s1;
    int ee = p & 511;
    dmat[((long)(b * 31 + node)) * 512 + ee] = v;
  }
}

// N=2 final layer with scatter table: one wave per row
__global__ __launch_bounds__(256) void rowdot2_k(
    const float* __restrict__ A, int lda,
    const float* __restrict__ W, const float* __restrict__ bias,
    int K, float* __restrict__ out, const int* __restrict__ scat)
{
  int wid = threadIdx.x >> 6, lane = threadIdx.x & 63;
  int r = blockIdx.x * 4 + wid;
  const float* a = A + (long)r * lda;
  float s0 = 0.f, s1 = 0.f;
  for (int k = lane; k < K; k += 64){
    float x = a[k];
    s0 = fmaf(x, W[k * 2], s0);
    s1 = fmaf(x, W[k * 2 + 1], s1);
  }
  for (int off = 32; off > 0; off >>= 1){
    s0 += __shfl_down(s0, off);
    s1 += __shfl_down(s1, off);
  }
  if (lane == 0){
    long o = scat[r];
    out[o] = s0 + bias[0];
    out[o + 1] = s1 + bias[1];
  }
}

// batched osl over all steps: grid 1920 (r = it*128 + b)
__global__ __launch_bounds__(256) void oslb_k(
    const float* __restrict__ pred, const float* __restrict__ u,
    const int* __restrict__ actions, float* __restrict__ sl, float* __restrict__ rew)
{
  int r = blockIdx.x, tid = threadIdx.x;
  int it = r >> 7, b = r & 127;
  int s0 = actions[(b * 15 + it) * 2];
  int s1 = actions[(b * 15 + it) * 2 + 1];
  const float* t0 = u + ((long)(b * 31 + s0)) * 512;
  const float* t1 = u + ((long)(b * 31 + s1)) * 512;
  const float* p = pred + (long)r * 1024;
  float s = 0.f;
  for (int k = tid; k < 512; k += 256){
    float d0 = p[k] - t0[k];       s = fmaf(d0, d0, s);
    float d1 = p[k + 512] - t1[k]; s = fmaf(d1, d1, s);
  }
  __shared__ float red[256];
  red[tid] = s; __syncthreads();
  for (int st = 128; st > 0; st >>= 1){ if (tid < st) red[tid] += red[tid + st]; __syncthreads(); }
  if (tid == 0){
    float osl = red[0] / 1024.0f;
    atomicAdd(sl + b, osl);
    rew[b * 15 + it] = -osl;
  }
}

// ---------------- init (no dmat zeroing: every cell of d is provably overwritten) ----------------
__global__ __launch_bounds__(256) void init_k(float* __restrict__ lbl,
    float* __restrict__ logits, float* __restrict__ sl, float* __restrict__ ent,
    int* __restrict__ active, float* __restrict__ zb,
    float* __restrict__ W1cat, const float* __restrict__ pol_w1, const float* __restrict__ pol_b3,
    long* __restrict__ tab_init, int* __restrict__ scat_init, long* __restrict__ tab_tok16,
    long* __restrict__ tab_mgd, int* __restrict__ scat_clf, long clf_off)
{
  long i = (long)blockIdx.x * 256 + threadIdx.x;
  if (i < 524288L){
    int k = (int)(i >> 10), n = (int)(i & 1023);
    W1cat[i] = (n < 512) ? pol_w1[(long)k * 512 + n] : pol_w1[(long)(k + 512) * 512 + (n - 512)];
  }
  if (i < 115200L){
    int rem = (int)(i % 900);
    int rr = rem / 30, cc = rem % 30;
    logits[i] = (rr < 16 && cc < 16 && rr != cc) ? pol_b3[0] : MASKV;
  }
  if (i < 30720L){
    int r = (int)i;
    int pk = r >> 7, b = r & 127;
    int ii2 = pk / 15, jr = pk % 15;
    int jj2 = jr + (jr >= ii2 ? 1 : 0);
    tab_init[r * 2]     = ((long)(b * 31 + ii2)) * 1024;
    tab_init[r * 2 + 1] = ((long)(b * 31 + jj2)) * 1024 + 512;
    scat_init[r] = b * 900 + ii2 * 30 + jj2;
  }
  if (i < 3968L){
    lbl[i] = ((i % 31) < 15) ? 1.0f : 0.0f;
    int r = (int)i;
    if (r < 1920){
      scat_clf[r] = (int)(clf_off + (long)(r & 127) * 62 + (r >> 7) * 2);
    } else {
      int rr = r - 1920;
      scat_clf[r] = (int)(clf_off + (long)(rr >> 4) * 62 + 60 - ((rr & 15) << 1));
    }
  }
  if (i < 2048L){
    active[i] = (int)(i & 15);
    tab_tok16[i] = ((long)((i >> 4) * 31 + (i & 15))) * 512;
  }
  if (i < 1920L){
    int it = (int)(i >> 7), b = (int)(i & 127);
    tab_mgd[i] = ((long)(b * 31 + 30 - it)) * 512;
  }
  if (i < 1024L)  zb[i] = 0.f;
  if (i < 128L){ sl[i] = 0.f; ent[i] = 0.f; }
}

__global__ __launch_bounds__(256) void noise_u_k(float* __restrict__ u, uint32_t k0, uint32_t k1){
  uint32_t e = blockIdx.x * 256u + threadIdx.x; // < 1048576
  uint32_t b = e >> 13, rem = e & 8191u, n = rem >> 9, ee = rem & 511u;
  float nr = jax_normal(k0, k1, e);
  long off = ((long)(b * 31u + n)) * 512 + ee;
  u[off] += 0.01f * nr;
}

__global__ __launch_bounds__(256) void build_d_k(float* __restrict__ dmat, const float* __restrict__ u){
  int e = blockIdx.x * 256 + threadIdx.x; // 65536
  int b = e >> 9, ee = e & 511;
  long off = ((long)(b * 31 + 30)) * 512 + ee;
  dmat[off] = u[off];
}

__global__ __launch_bounds__(256) void finalize_k(const float* __restrict__ rew,
    const float* __restrict__ lp, const float* __restrict__ sl, const float* __restrict__ ent,
    float* __restrict__ out_sl, float* __restrict__ out_ent, float* __restrict__ out_reinf)
{
  __shared__ float red[256];
  int tid = threadIdx.x;
  float s = 0.f;
  for (int i = tid; i < 1920; i += 256) s += rew[i];
  red[tid] = s; __syncthreads();
  for (int st = 128; st > 0; st >>= 1){ if (tid < st) red[tid] += red[tid + st]; __syncthreads(); }
  float mean = red[0] / 1920.0f; __syncthreads();
  float v = 0.f;
  for (int i = tid; i < 1920; i += 256){ float x = rew[i] - mean; v = fmaf(x, x, v); }
  red[tid] = v; __syncthreads();
  for (int st = 128; st > 0; st >>= 1){ if (tid < st) red[tid] += red[tid + st]; __syncthreads(); }
  float denom = sqrtf(red[0] / 1919.0f) + 1e-20f;
  if (tid < 128){
    out_sl[tid] = sl[tid] / 15.0f;
    out_ent[tid] = ent[tid] / 15.0f;
    float r = 0.f;
    for (int k = 0; k < 15; k++){
      float rn = (rew[tid * 15 + k] - mean) / denom;
      r = fmaf(lp[tid * 15 + k], rn, r);
    }
    out_reinf[tid] = r;
  }
}

// ---------------- host ----------------
extern "C" void kernel_launch(void* const* d_in, const int* in_sizes, int n_in,
                              void* d_out, int out_size, void* d_ws, size_t ws_size,
                              hipStream_t stream)
{
  const float* x        = (const float*)d_in[0];
  const float* lift_w   = (const float*)d_in[1];
  const float* lift_b   = (const float*)d_in[2];
  const float* unlift_w = (const float*)d_in[3];
  const float* unlift_b = (const float*)d_in[4];
  const float* enc_w1   = (const float*)d_in[5];
  const float* enc_b1   = (const float*)d_in[6];
  const float* enc_w2   = (const float*)d_in[7];
  const float* enc_b2   = (const float*)d_in[8];
  const float* enc_w3   = (const float*)d_in[9];
  const float* enc_b3   = (const float*)d_in[10];
  const float* dec_w1   = (const float*)d_in[11];
  const float* dec_b1   = (const float*)d_in[12];
  const float* dec_w2   = (const float*)d_in[13];
  const float* dec_b2   = (const float*)d_in[14];
  const float* dec_w3   = (const float*)d_in[15];
  const float* dec_b3   = (const float*)d_in[16];
  const float* clf_w1   = (const float*)d_in[17];
  const float* clf_b1   = (const float*)d_in[18];
  const float* clf_w2   = (const float*)d_in[19];
  const float* clf_b2   = (const float*)d_in[20];
  const float* clf_w3   = (const float*)d_in[21];
  const float* clf_b3   = (const float*)d_in[22];
  const float* pol_w1   = (const float*)d_in[23];
  const float* pol_b1   = (const float*)d_in[24];
  const float* pol_w2   = (const float*)d_in[25];
  const float* pol_b2   = (const float*)d_in[26];
  const float* pol_w3   = (const float*)d_in[27];
  const float* pol_b3   = (const float*)d_in[28];

  float* out = (float*)d_out;
  const long U_OFF     = 2097152;
  const long D_OFF     = 4128768;
  const long SL_OFF    = 6160384;
  const long ENT_OFF   = 6160512;
  const long CLF_OFF   = 6160640;
  const long LBL_OFF   = 6168576;
  const long REINF_OFF = 6172544;
  float* recon = out;
  float* u     = out + U_OFF;
  float* dmat  = out + D_OFF;

  char* wsb = (char*)d_ws;
  size_t wo = 0;
  auto alloc = [&](size_t bytes) -> void* {
    void* p = (void*)(wsb + wo);
    wo = (wo + bytes + 255) & ~(size_t)255;
    return p;
  };
  float* logits    = (float*)alloc(115200 * 4);
  float* Y         = (float*)alloc((size_t)3968 * 1024 * 4); // dead after fwd -> overlays:
  float* h1clf     = Y;                  // tail clf hidden1 (3968x512)
  float* pbuf      = Y + 2031616;        // dec output 1920x1024, then clf h2
  float* h2clf     = Y + 2031616;
  float* W1cat     = (float*)alloc((size_t)524288 * 4);
  float* zb        = (float*)alloc(1024 * 4);
  float* h1        = (float*)alloc((size_t)2048 * 512 * 4);
  float* h2        = (float*)alloc((size_t)2048 * 512 * 4);
  float* z_all     = (float*)alloc((size_t)15 * 65536 * 4);
  float* sl        = (float*)alloc(128 * 4);
  float* ent       = (float*)alloc(128 * 4);
  float* lp        = (float*)alloc(1920 * 4);
  float* rew       = (float*)alloc(1920 * 4);
  int*   active    = (int*)alloc(2048 * 4);
  int*   actions   = (int*)alloc(3840 * 4);
  long*  tab_init  = (long*)alloc((size_t)30720 * 2 * 8);
  int*   scat_init = (int*)alloc(30720 * 4);
  long*  tab_loop  = (long*)alloc((size_t)3584 * 2 * 8);
  int*   scat_loop = (int*)alloc(3584 * 4);
  long*  tab_pair  = (long*)alloc(256 * 8);
  long*  tab_mgd   = (long*)alloc(1920 * 8);   // contiguous with tab_tok16 -> 3968-row clf table
  long*  tab_tok16 = (long*)alloc(2048 * 8);
  int*   scat_clf  = (int*)alloc(3968 * 4);
  long*  tab_clf   = tab_mgd;
  (void)ws_size; (void)in_sizes; (void)n_in; (void)out_size;

  uint32_t k7a, k7b, ck0[15], ck1[15], mk0[15], mk1[15];
  { uint32_t a = 0, b = 7; tf2x32(0u, 42u, a, b); k7a = a; k7b = b; }
  for (int it = 0; it < 15; it++){
    { uint32_t a = 0, b = (uint32_t)(100 + it); tf2x32(0u, 42u, a, b); ck0[it] = a; ck1[it] = b; }
    { uint32_t a = 0, b = (uint32_t)(1000 + it); tf2x32(0u, 42u, a, b); mk0[it] = a; mk1[it] = b; }
  }

  auto gemm = [&](int act, const float* A, int lda, const long* atab, int anblk,
                  const float* W, const float* bs, float* C, int rows, int K, int Nn,
                  long cb, int crd, long cos, long cis){
    dim3 g(Nn / 64, rows / 64);
    if (act) gemm_k<1><<<g, 256, 0, stream>>>(A, lda, atab, anblk, W, bs, C, K, Nn, cb, crd, cos, cis);
    else     gemm_k<0><<<g, 256, 0, stream>>>(A, lda, atab, anblk, W, bs, C, K, Nn, cb, crd, cos, cis);
  };

  // ---- init ----
  init_k<<<2048, 256, 0, stream>>>(out + LBL_OFF, logits, sl, ent, active, zb,
                                   W1cat, pol_w1, pol_b3, tab_init, scat_init, tab_tok16,
                                   tab_mgd, scat_clf, CLF_OFF);

  // ---- lift + noise ----
  gemm(0, x, 1024, nullptr, 0, lift_w, lift_b, u, 2048, 1024, 512, 0, 16, 15872, 512);
  noise_u_k<<<4096, 256, 0, stream>>>(u, k7a, k7b);

  // ---- Y init for tokens 0..15 ----
  gemm(0, u, 0, tab_tok16, 1, W1cat, zb, Y, 2048, 512, 1024, 0, 16, 31744, 1024);

  // ---- initial policy logits ----
  { dim3 g(4, 120);
    gemm128f_k<<<g, 512, 0, stream>>>(Y, tab_init, pol_b1, pol_w2, pol_b2, pol_w3,
                                      scat_init, logits); }

  // ---- forward merge loop: 2 cooperative launches per iteration ----
  for (int it = 0; it < 15; it++){
    int A = 16 - it;
    int nrb = (it > 0) ? 4 * (15 - it) : 0;   // gemm64f row-blocks (rows/64)
    int gdim = (8 * nrb > 128) ? 8 * nrb : 128;
    float log_opt = (float)log((double)(A * (A - 1)));
    int it_v = it, A_v = A;
    uint32_t c0v = ck0[it], c1v = ck1[it];
    void* a1[] = { (void*)&Y, (void*)&pol_b1, (void*)&pol_w2, (void*)&pol_b2, (void*)&pol_w3,
                   (void*)&logits, (void*)&nrb,
                   (void*)&active, (void*)&actions, (void*)&lp, (void*)&ent,
                   (void*)&it_v, (void*)&A_v, (void*)&c0v, (void*)&c1v, (void*)&log_opt,
                   (void*)&tab_loop, (void*)&scat_loop, (void*)&tab_pair, (void*)&pol_b3 };
    hipLaunchCooperativeKernel((const void*)gs_k, dim3(gdim), dim3(256), a1, 0, stream);

    uint32_t m0 = mk0[it], m1 = mk1[it];
    void* a2[] = { (void*)&u, (void*)&tab_pair,
                   (void*)&enc_w1, (void*)&enc_b1, (void*)&enc_w2, (void*)&enc_b2,
                   (void*)&enc_w3, (void*)&enc_b3,
                   (void*)&W1cat, (void*)&z_all, (void*)&Y,
                   (void*)&it_v, (void*)&m0, (void*)&m1, (void*)&h1, (void*)&h2 };
    hipLaunchCooperativeKernel((const void*)encchain_k, dim3(512), dim3(256), a2, 0, stream);
  }

  // ---- deferred batched dec over all 15 steps (1920 rows), then osl ----
  gemm(1, z_all, 512, nullptr, 0, dec_w1, dec_b1, h1, 1920, 512, 512, 0, 1, 512, 0);
  gemm(1, h1, 512, nullptr, 0, dec_w2, dec_b2, h2, 1920, 512, 512, 0, 1, 512, 0);
  gemm(0, h2, 512, nullptr, 0, dec_w3, dec_b3, pbuf, 1920, 512, 1024, 0, 1, 1024, 0);
  oslb_k<<<1920, 256, 0, stream>>>(pbuf, u, actions, sl, rew);

  // ---- d init (only token 30 active) ----
  build_d_k<<<256, 256, 0, stream>>>(dmat, u);

  // ---- reverse unmerge loop: 1 cooperative launch per step ----
  for (int it = 0; it < 15; it++){
    int it_v = it;
    void* a3[] = { (void*)&dmat,
                   (void*)&dec_w1, (void*)&dec_b1, (void*)&dec_w2, (void*)&dec_b2,
                   (void*)&dec_w3, (void*)&dec_b3,
                   (void*)&actions, (void*)&it_v, (void*)&h1, (void*)&h2 };
    hipLaunchCooperativeKernel((const void*)revchain_k, dim3(512), dim3(256), a3, 0, stream);
  }

  // ---- combined clf over mgd rows (1920) + final d[:, :16] rows (2048) ----
  gemm(1, dmat, 0, tab_clf, 1, clf_w1, clf_b1, h1clf, 3968, 512, 512, 0, 1, 512, 0);
  gemm(1, h1clf, 512, nullptr, 0, clf_w2, clf_b2, h2clf, 3968, 512, 512, 0, 1, 512, 0);
  rowdot2_k<<<992, 256, 0, stream>>>(h2clf, 512, clf_w3, clf_b3, 512, out, scat_clf);

  // ---- recon = d[:, :16] @ unlift_w + unlift_b ----
  gemm(0, dmat, 0, tab_tok16, 1, unlift_w, unlift_b, recon, 2048, 512, 1024,
       0, 16, 16384, 1024);

  // ---- reward normalization, reinf, per-batch losses ----
  finalize_k<<<1, 256, 0, stream>>>(rew, lp, sl, ent,
                                    out + SL_OFF, out + ENT_OFF, out + REINF_OFF);
}

// Round 9
// 2513.213 us; speedup vs baseline: 2.8773x; 2.8773x over previous
//
#include <hip/hip_runtime.h>
#include <cstdint>
#include <cmath>

#define MASKV -9.0e20f

// ---------------- Threefry-2x32 (JAX-compatible) ----------------
__host__ __device__ inline void tf2x32(uint32_t k0, uint32_t k1, uint32_t& x0, uint32_t& x1){
  uint32_t ks2 = k0 ^ k1 ^ 0x1BD11BDAu;
  x0 += k0; x1 += k1;
#define TFR(r) { x0 += x1; x1 = (x1<<(r))|(x1>>(32-(r))); x1 ^= x0; }
  TFR(13) TFR(15) TFR(26) TFR(6)
  x0 += k1;  x1 += ks2 + 1u;
  TFR(17) TFR(29) TFR(16) TFR(24)
  x0 += ks2; x1 += k0 + 2u;
  TFR(13) TFR(15) TFR(26) TFR(6)
  x0 += k0;  x1 += k1 + 3u;
  TFR(17) TFR(29) TFR(16) TFR(24)
  x0 += k1;  x1 += ks2 + 4u;
  TFR(13) TFR(15) TFR(26) TFR(6)
  x0 += ks2; x1 += k0 + 5u;
#undef TFR
}

__device__ inline uint32_t rbits32(uint32_t k0, uint32_t k1, uint32_t idx){
  uint32_t x0 = 0u, x1 = idx;
  tf2x32(k0, k1, x0, x1);
  return x0 ^ x1;
}

__device__ inline float u01_from_bits(uint32_t bits){
  union { uint32_t u; float f; } c;
  c.u = (bits >> 9) | 0x3f800000u;
  return c.f - 1.0f;
}

__device__ inline float erfinv_f(float x){
  float w = -log1pf(-x*x);
  float p;
  if (w < 5.0f){
    w -= 2.5f;
    p = 2.81022636e-08f;
    p = fmaf(p, w, 3.43273939e-07f);
    p = fmaf(p, w, -3.5233877e-06f);
    p = fmaf(p, w, -4.39150654e-06f);
    p = fmaf(p, w, 0.00021858087f);
    p = fmaf(p, w, -0.00125372503f);
    p = fmaf(p, w, -0.00417768164f);
    p = fmaf(p, w, 0.246640727f);
    p = fmaf(p, w, 1.50140941f);
  } else {
    w = sqrtf(w) - 3.0f;
    p = -0.000200214257f;
    p = fmaf(p, w, 0.000100950558f);
    p = fmaf(p, w, 0.00134934322f);
    p = fmaf(p, w, -0.00367342844f);
    p = fmaf(p, w, 0.00573950773f);
    p = fmaf(p, w, -0.0076224613f);
    p = fmaf(p, w, 0.00943887047f);
    p = fmaf(p, w, 1.00167406f);
    p = fmaf(p, w, 2.83297682f);
  }
  return p * x;
}

__device__ inline float jax_normal(uint32_t k0, uint32_t k1, uint32_t idx){
  float f = u01_from_bits(rbits32(k0, k1, idx));
  float v = fmaf(f, 2.0f, -0.99999994f);
  v = fmaxf(v, -0.99999994f);
  return 1.41421356f * erfinv_f(v);
}

__device__ inline float jax_gumbel(uint32_t k0, uint32_t k1, uint32_t idx){
  float f = u01_from_bits(rbits32(k0, k1, idx));
  f = f + 1.17549435e-38f;
  f = fmaxf(f, 1.17549435e-38f);
  return -logf(-logf(f));
}

// ---------------- small tiled SGEMM (64x64 tile, 4x4 microtile) ----------------
template<int ACT>
__global__ __launch_bounds__(256) void gemm_k(
    const float* __restrict__ A, int lda,
    const long* __restrict__ atab, int anblk,
    const float* __restrict__ W, const float* __restrict__ bias,
    float* __restrict__ C, int K, int N,
    long c_base, int c_rdiv, long c_ostride, long c_istride)
{
  __shared__ float As[16][64];
  __shared__ float Ws[16][64];
  int tid = threadIdx.x;
  int c0 = blockIdx.x * 64;
  int r0 = blockIdx.y * 64;
  int lr = tid >> 2;
  int lk = (tid & 3) << 2;
  int wk = tid >> 4;
  int wc = (tid & 15) << 2;
  int tx = tid & 15;
  int ty = tid >> 4;
  long aoff0 = 0, aoff1 = 0;
  if (atab){
    const long* t = atab + (long)(r0 + lr) * anblk;
    aoff0 = t[0];
    if (anblk == 2) aoff1 = t[1];
  } else {
    aoff0 = (long)(r0 + lr) * lda;
  }
  float acc[4][4];
#pragma unroll
  for (int i = 0; i < 4; i++)
#pragma unroll
    for (int j = 0; j < 4; j++) acc[i][j] = 0.f;

  for (int k0 = 0; k0 < K; k0 += 16){
    int ka = k0 + lk;
    long ab = (atab && anblk == 2 && ka >= 512) ? (aoff1 + (ka - 512)) : (aoff0 + ka);
    float4 av = *(const float4*)(A + ab);
    As[lk + 0][lr] = av.x;
    As[lk + 1][lr] = av.y;
    As[lk + 2][lr] = av.z;
    As[lk + 3][lr] = av.w;
    float4 wv = *(const float4*)(W + (long)(k0 + wk) * N + (c0 + wc));
    *(float4*)&Ws[wk][wc] = wv;
    __syncthreads();
#pragma unroll
    for (int kk = 0; kk < 16; kk++){
      float4 a4 = *(const float4*)&As[kk][ty << 2];
      float4 w4 = *(const float4*)&Ws[kk][tx << 2];
      float aa[4] = {a4.x, a4.y, a4.z, a4.w};
      float ww[4] = {w4.x, w4.y, w4.z, w4.w};
#pragma unroll
      for (int i = 0; i < 4; i++)
#pragma unroll
        for (int j = 0; j < 4; j++)
          acc[i][j] = fmaf(aa[i], ww[j], acc[i][j]);
    }
    __syncthreads();
  }
  float4 bv = *(const float4*)(bias + c0 + (tx << 2));
  float bb[4] = {bv.x, bv.y, bv.z, bv.w};
#pragma unroll
  for (int i = 0; i < 4; i++){
    int r = r0 + (ty << 2) + i;
    long off = c_base + (long)(r / c_rdiv) * c_ostride + (long)(r % c_rdiv) * c_istride
               + c0 + (tx << 2);
    float4 v;
    float o0 = acc[i][0] + bb[0], o1 = acc[i][1] + bb[1];
    float o2 = acc[i][2] + bb[2], o3 = acc[i][3] + bb[3];
    if (ACT){ o0 = fmaxf(o0, 0.f); o1 = fmaxf(o1, 0.f); o2 = fmaxf(o2, 0.f); o3 = fmaxf(o3, 0.f); }
    v.x = o0; v.y = o1; v.z = o2; v.w = o3;
    *(float4*)(C + off) = v;
  }
}

// ---------------- 256x128-tile fused policy GEMM (measured-best: 216us, VGPR 52) ----------------
// 512 threads / 8 waves, 8x8 microtile. At the ds_read_b128 throughput cap
// (85 B/cyc vs 128 B/cyc demand at 0.25 LDS-floats/FMA -> VALUBusy ~62%).
__global__ __launch_bounds__(512, 4) void gemm128f_k(
    const float* __restrict__ Y,
    const long* __restrict__ atab,
    const float* __restrict__ b1,
    const float* __restrict__ W2, const float* __restrict__ b2,
    const float* __restrict__ w3,
    const int* __restrict__ scat, float* __restrict__ logits)
{
  __shared__ float As[16][260];
  __shared__ float Ws[16][132];
  int tid = threadIdx.x;
  int c0 = blockIdx.x * 128;
  int r0 = blockIdx.y * 256;
  int tx = tid & 15, ty = tid >> 4;   // ty in [0,32): 8 rows each
  int rA = tid >> 1;                  // [0,256): staged A-row
  int kh = (tid & 1) << 3;            // 0 or 8
  long a0r = atab[(long)(r0 + rA) * 2];
  long a1r = atab[(long)(r0 + rA) * 2 + 1];
  int wk = tid >> 5;                  // [0,16)
  int wc = (tid & 31) << 2;           // [0,128)
  float acc[8][8];
#pragma unroll
  for (int i = 0; i < 8; i++)
#pragma unroll
    for (int j = 0; j < 8; j++) acc[i][j] = 0.f;

  for (int k0 = 0; k0 < 512; k0 += 16){
    float4 p0 = *(const float4*)(Y + a0r + k0 + kh);
    float4 p1 = *(const float4*)(Y + a0r + k0 + kh + 4);
    float4 q0 = *(const float4*)(Y + a1r + k0 + kh);
    float4 q1 = *(const float4*)(Y + a1r + k0 + kh + 4);
    float4 bv0 = *(const float4*)(b1 + k0 + kh);
    float4 bv1 = *(const float4*)(b1 + k0 + kh + 4);
    As[kh + 0][rA] = fmaxf(p0.x + q0.x + bv0.x, 0.f);
    As[kh + 1][rA] = fmaxf(p0.y + q0.y + bv0.y, 0.f);
    As[kh + 2][rA] = fmaxf(p0.z + q0.z + bv0.z, 0.f);
    As[kh + 3][rA] = fmaxf(p0.w + q0.w + bv0.w, 0.f);
    As[kh + 4][rA] = fmaxf(p1.x + q1.x + bv1.x, 0.f);
    As[kh + 5][rA] = fmaxf(p1.y + q1.y + bv1.y, 0.f);
    As[kh + 6][rA] = fmaxf(p1.z + q1.z + bv1.z, 0.f);
    As[kh + 7][rA] = fmaxf(p1.w + q1.w + bv1.w, 0.f);
    *(float4*)&Ws[wk][wc] = *(const float4*)(W2 + (long)(k0 + wk) * 512 + (c0 + wc));
    __syncthreads();
#pragma unroll
    for (int kk = 0; kk < 16; kk++){
      float a8[8], w8[8];
      *(float4*)&a8[0] = *(const float4*)&As[kk][ty << 3];
      *(float4*)&a8[4] = *(const float4*)&As[kk][(ty << 3) + 4];
      *(float4*)&w8[0] = *(const float4*)&Ws[kk][tx << 2];
      *(float4*)&w8[4] = *(const float4*)&Ws[kk][(tx << 2) + 64];
#pragma unroll
      for (int i = 0; i < 8; i++)
#pragma unroll
        for (int j = 0; j < 8; j++)
          acc[i][j] = fmaf(a8[i], w8[j], acc[i][j]);
    }
    __syncthreads();
  }
  float bb[8], w3v[8];
  *(float4*)&bb[0]  = *(const float4*)(b2 + c0 + (tx << 2));
  *(float4*)&bb[4]  = *(const float4*)(b2 + c0 + (tx << 2) + 64);
  *(float4*)&w3v[0] = *(const float4*)(w3 + c0 + (tx << 2));
  *(float4*)&w3v[4] = *(const float4*)(w3 + c0 + (tx << 2) + 64);
#pragma unroll
  for (int i = 0; i < 8; i++){
    float p = 0.f;
#pragma unroll
    for (int j = 0; j < 8; j++)
      p = fmaf(fmaxf(acc[i][j] + bb[j], 0.f), w3v[j], p);
    for (int m = 1; m < 16; m <<= 1) p += __shfl_xor(p, m);
    if (tx == 0){
      int rr = (ty << 3) + i;
      atomicAdd(logits + scat[r0 + rr], p);
    }
  }
}

// ---------------- 64-tile fused policy GEMM (in-loop, rows <= 3584) ----------------
// 64x64 4x4: small tiles maximize block count for underfilled late iterations.
__global__ __launch_bounds__(256) void gemm64f_k(
    const float* __restrict__ Y,
    const long* __restrict__ atab,
    const float* __restrict__ b1,
    const float* __restrict__ W2, const float* __restrict__ b2,
    const float* __restrict__ w3,
    const int* __restrict__ scat, float* __restrict__ logits)
{
  __shared__ float As[16][64];
  __shared__ float Ws[16][64];
  int tid = threadIdx.x;
  int c0 = blockIdx.x * 64;
  int r0 = blockIdx.y * 64;
  int lr = tid >> 2;
  int lk = (tid & 3) << 2;
  int wk = tid >> 4;
  int wc = (tid & 15) << 2;
  int tx = tid & 15;
  int ty = tid >> 4;
  long a0 = atab[(long)(r0 + lr) * 2];
  long a1 = atab[(long)(r0 + lr) * 2 + 1];
  float acc[4][4];
#pragma unroll
  for (int i = 0; i < 4; i++)
#pragma unroll
    for (int j = 0; j < 4; j++) acc[i][j] = 0.f;

  for (int k0 = 0; k0 < 512; k0 += 16){
    int ka = k0 + lk;
    float4 p = *(const float4*)(Y + a0 + ka);
    float4 q = *(const float4*)(Y + a1 + ka);
    float4 bb = *(const float4*)(b1 + ka);
    As[lk + 0][lr] = fmaxf(p.x + q.x + bb.x, 0.f);
    As[lk + 1][lr] = fmaxf(p.y + q.y + bb.y, 0.f);
    As[lk + 2][lr] = fmaxf(p.z + q.z + bb.z, 0.f);
    As[lk + 3][lr] = fmaxf(p.w + q.w + bb.w, 0.f);
    *(float4*)&Ws[wk][wc] = *(const float4*)(W2 + (long)(k0 + wk) * 512 + (c0 + wc));
    __syncthreads();
#pragma unroll
    for (int kk = 0; kk < 16; kk++){
      float4 a4 = *(const float4*)&As[kk][ty << 2];
      float4 w4 = *(const float4*)&Ws[kk][tx << 2];
      float aa[4] = {a4.x, a4.y, a4.z, a4.w};
      float ww[4] = {w4.x, w4.y, w4.z, w4.w};
#pragma unroll
      for (int i = 0; i < 4; i++)
#pragma unroll
        for (int j = 0; j < 4; j++)
          acc[i][j] = fmaf(aa[i], ww[j], acc[i][j]);
    }
    __syncthreads();
  }
  float bb4[4], w34[4];
  *(float4*)&bb4[0] = *(const float4*)(b2 + c0 + (tx << 2));
  *(float4*)&w34[0] = *(const float4*)(w3 + c0 + (tx << 2));
#pragma unroll
  for (int i = 0; i < 4; i++){
    float p = 0.f;
#pragma unroll
    for (int j = 0; j < 4; j++)
      p = fmaf(fmaxf(acc[i][j] + bb4[j], 0.f), w34[j], p);
    for (int m = 1; m < 16; m <<= 1) p += __shfl_xor(p, m);
    if (tx == 0){
      int r = r0 + (ty << 2) + i;
      atomicAdd(logits + scat[r], p);
    }
  }
}

// N=2 final layer with scatter table: one wave per row
__global__ __launch_bounds__(256) void rowdot2_k(
    const float* __restrict__ A, int lda,
    const float* __restrict__ W, const float* __restrict__ bias,
    int K, float* __restrict__ out, const int* __restrict__ scat)
{
  int wid = threadIdx.x >> 6, lane = threadIdx.x & 63;
  int r = blockIdx.x * 4 + wid;
  const float* a = A + (long)r * lda;
  float s0 = 0.f, s1 = 0.f;
  for (int k = lane; k < K; k += 64){
    float x = a[k];
    s0 = fmaf(x, W[k * 2], s0);
    s1 = fmaf(x, W[k * 2 + 1], s1);
  }
  for (int off = 32; off > 0; off >>= 1){
    s0 += __shfl_down(s0, off);
    s1 += __shfl_down(s1, off);
  }
  if (lane == 0){
    long o = scat[r];
    out[o] = s0 + bias[0];
    out[o + 1] = s1 + bias[1];
  }
}

// ---------------- wide per-layer matvec kernels (row/block, col/thread) ----------------
// enc layer1: src = pair gather (K=1024), C=512, relu. grid (2, 128)
__global__ __launch_bounds__(256) void pairmv_k(
    const float* __restrict__ u, const long* __restrict__ tab_pair,
    const float* __restrict__ W, const float* __restrict__ bias,
    float* __restrict__ dst)
{
  __shared__ float s[1024];
  int b = blockIdx.y, tid = threadIdx.x;
  int c = blockIdx.x * 256 + tid;
  long t0 = tab_pair[b * 2], t1 = tab_pair[b * 2 + 1];
  s[tid]       = u[t0 + tid];
  s[tid + 256] = u[t0 + tid + 256];
  s[tid + 512] = u[t1 + tid];
  s[tid + 768] = u[t1 + tid + 256];
  __syncthreads();
  float a0 = 0.f, a1 = 0.f, a2 = 0.f, a3 = 0.f;
#pragma unroll 8
  for (int k = 0; k < 1024; k += 4){
    a0 = fmaf(s[k],     W[(long)k * 512 + c],       a0);
    a1 = fmaf(s[k + 1], W[(long)(k + 1) * 512 + c], a1);
    a2 = fmaf(s[k + 2], W[(long)(k + 2) * 512 + c], a2);
    a3 = fmaf(s[k + 3], W[(long)(k + 3) * 512 + c], a3);
  }
  float v = ((a0 + a1) + (a2 + a3)) + bias[c];
  dst[(long)b * 512 + c] = fmaxf(v, 0.f);
}

// generic K=512 -> C=512 relu layer. grid (2, 128)
__global__ __launch_bounds__(256) void mvrelu_k(
    const float* __restrict__ src, long sstride,
    const float* __restrict__ W, const float* __restrict__ bias,
    float* __restrict__ dst)
{
  __shared__ float s[512];
  int b = blockIdx.y, tid = threadIdx.x;
  int c = blockIdx.x * 256 + tid;
  const float* sr = src + (long)b * sstride;
  s[tid] = sr[tid];
  s[tid + 256] = sr[tid + 256];
  __syncthreads();
  float a0 = 0.f, a1 = 0.f, a2 = 0.f, a3 = 0.f;
#pragma unroll 8
  for (int k = 0; k < 512; k += 4){
    a0 = fmaf(s[k],     W[(long)k * 512 + c],       a0);
    a1 = fmaf(s[k + 1], W[(long)(k + 1) * 512 + c], a1);
    a2 = fmaf(s[k + 2], W[(long)(k + 2) * 512 + c], a2);
    a3 = fmaf(s[k + 3], W[(long)(k + 3) * 512 + c], a3);
  }
  float v = ((a0 + a1) + (a2 + a3)) + bias[c];
  dst[(long)b * 512 + c] = fmaxf(v, 0.f);
}

// enc layer3: z = h2@W + b (no relu); store z, and u token row = z + noise. grid (2, 128)
__global__ __launch_bounds__(256) void lay3z_k(
    const float* __restrict__ src,
    const float* __restrict__ W, const float* __restrict__ bias,
    float* __restrict__ z_all, float* __restrict__ u,
    int it, uint32_t k0, uint32_t k1)
{
  __shared__ float s[512];
  int b = blockIdx.y, tid = threadIdx.x;
  int c = blockIdx.x * 256 + tid;
  const float* sr = src + (long)b * 512;
  s[tid] = sr[tid];
  s[tid + 256] = sr[tid + 256];
  __syncthreads();
  float a0 = 0.f, a1 = 0.f, a2 = 0.f, a3 = 0.f;
#pragma unroll 8
  for (int k = 0; k < 512; k += 4){
    a0 = fmaf(s[k],     W[(long)k * 512 + c],       a0);
    a1 = fmaf(s[k + 1], W[(long)(k + 1) * 512 + c], a1);
    a2 = fmaf(s[k + 2], W[(long)(k + 2) * 512 + c], a2);
    a3 = fmaf(s[k + 3], W[(long)(k + 3) * 512 + c], a3);
  }
  float v = ((a0 + a1) + (a2 + a3)) + bias[c];
  z_all[(long)it * 65536 + (long)b * 512 + c] = v;
  float nv = jax_normal(k0, k1, (uint32_t)(b * 512 + c));
  u[((long)(b * 31 + 16 + it)) * 512 + c] = v + 0.01f * nv;
}

// Y row for new token: Y[tok] = u[tok] @ W1cat (no bias). grid (4, 128)
__global__ __launch_bounds__(256) void yrow_k(
    const float* __restrict__ u, const float* __restrict__ W1cat,
    float* __restrict__ Y, int it)
{
  __shared__ float s[512];
  int b = blockIdx.y, tid = threadIdx.x;
  int c = blockIdx.x * 256 + tid;
  const float* sr = u + ((long)(b * 31 + 16 + it)) * 512;
  s[tid] = sr[tid];
  s[tid + 256] = sr[tid + 256];
  __syncthreads();
  float a0 = 0.f, a1 = 0.f, a2 = 0.f, a3 = 0.f;
#pragma unroll 8
  for (int k = 0; k < 512; k += 4){
    a0 = fmaf(s[k],     W1cat[(long)k * 1024 + c],       a0);
    a1 = fmaf(s[k + 1], W1cat[(long)(k + 1) * 1024 + c], a1);
    a2 = fmaf(s[k + 2], W1cat[(long)(k + 2) * 1024 + c], a2);
    a3 = fmaf(s[k + 3], W1cat[(long)(k + 3) * 1024 + c], a3);
  }
  Y[((long)(b * 31 + 16 + it)) * 1024 + c] = (a0 + a1) + (a2 + a3);
}

// reverse layer3 + scatter into dmat. grid (4, 128)
__global__ __launch_bounds__(256) void rev3_k(
    const float* __restrict__ src,
    const float* __restrict__ W, const float* __restrict__ bias,
    float* __restrict__ dmat, const int* __restrict__ actions, int it)
{
  __shared__ float s[512];
  int b = blockIdx.y, tid = threadIdx.x;
  int p = blockIdx.x * 256 + tid;
  const float* sr = src + (long)b * 512;
  s[tid] = sr[tid];
  s[tid + 256] = sr[tid + 256];
  __syncthreads();
  float a0 = 0.f, a1 = 0.f, a2 = 0.f, a3 = 0.f;
#pragma unroll 8
  for (int k = 0; k < 512; k += 4){
    a0 = fmaf(s[k],     W[(long)k * 1024 + p],       a0);
    a1 = fmaf(s[k + 1], W[(long)(k + 1) * 1024 + p], a1);
    a2 = fmaf(s[k + 2], W[(long)(k + 2) * 1024 + p], a2);
    a3 = fmaf(s[k + 3], W[(long)(k + 3) * 1024 + p], a3);
  }
  float v = ((a0 + a1) + (a2 + a3)) + bias[p];
  int fit = 14 - it;
  int s0 = actions[(b * 15 + fit) * 2];
  int s1 = actions[(b * 15 + fit) * 2 + 1];
  int node = (p < 512) ? s0 : s1;
  int ee = p & 511;
  dmat[((long)(b * 31 + node)) * 512 + ee] = v;
}

// batched osl over all steps: grid 1920 (r = it*128 + b)
__global__ __launch_bounds__(256) void oslb_k(
    const float* __restrict__ pred, const float* __restrict__ u,
    const int* __restrict__ actions, float* __restrict__ sl, float* __restrict__ rew)
{
  int r = blockIdx.x, tid = threadIdx.x;
  int it = r >> 7, b = r & 127;
  int s0 = actions[(b * 15 + it) * 2];
  int s1 = actions[(b * 15 + it) * 2 + 1];
  const float* t0 = u + ((long)(b * 31 + s0)) * 512;
  const float* t1 = u + ((long)(b * 31 + s1)) * 512;
  const float* p = pred + (long)r * 1024;
  float s = 0.f;
  for (int k = tid; k < 512; k += 256){
    float d0 = p[k] - t0[k];       s = fmaf(d0, d0, s);
    float d1 = p[k + 512] - t1[k]; s = fmaf(d1, d1, s);
  }
  __shared__ float red[256];
  red[tid] = s; __syncthreads();
  for (int st = 128; st > 0; st >>= 1){ if (tid < st) red[tid] += red[tid + st]; __syncthreads(); }
  if (tid == 0){
    float osl = red[0] / 1024.0f;
    atomicAdd(sl + b, osl);
    rew[b * 15 + it] = -osl;
  }
}

// ---------------- init (no dmat zeroing: every cell of d is provably overwritten) ----------------
__global__ __launch_bounds__(256) void init_k(float* __restrict__ lbl,
    float* __restrict__ logits, float* __restrict__ sl, float* __restrict__ ent,
    int* __restrict__ active, float* __restrict__ zb,
    float* __restrict__ W1cat, const float* __restrict__ pol_w1, const float* __restrict__ pol_b3,
    long* __restrict__ tab_init, int* __restrict__ scat_init, long* __restrict__ tab_tok16,
    long* __restrict__ tab_mgd, int* __restrict__ scat_clf, long clf_off)
{
  long i = (long)blockIdx.x * 256 + threadIdx.x;
  if (i < 524288L){
    int k = (int)(i >> 10), n = (int)(i & 1023);
    W1cat[i] = (n < 512) ? pol_w1[(long)k * 512 + n] : pol_w1[(long)(k + 512) * 512 + (n - 512)];
  }
  if (i < 115200L){
    int rem = (int)(i % 900);
    int rr = rem / 30, cc = rem % 30;
    logits[i] = (rr < 16 && cc < 16 && rr != cc) ? pol_b3[0] : MASKV;
  }
  if (i < 30720L){
    int r = (int)i;
    int pk = r >> 7, b = r & 127;
    int ii2 = pk / 15, jr = pk % 15;
    int jj2 = jr + (jr >= ii2 ? 1 : 0);
    tab_init[r * 2]     = ((long)(b * 31 + ii2)) * 1024;
    tab_init[r * 2 + 1] = ((long)(b * 31 + jj2)) * 1024 + 512;
    scat_init[r] = b * 900 + ii2 * 30 + jj2;
  }
  if (i < 3968L){
    lbl[i] = ((i % 31) < 15) ? 1.0f : 0.0f;
    int r = (int)i;
    if (r < 1920){
      scat_clf[r] = (int)(clf_off + (long)(r & 127) * 62 + (r >> 7) * 2);
    } else {
      int rr = r - 1920;
      scat_clf[r] = (int)(clf_off + (long)(rr >> 4) * 62 + 60 - ((rr & 15) << 1));
    }
  }
  if (i < 2048L){
    active[i] = (int)(i & 15);
    tab_tok16[i] = ((long)((i >> 4) * 31 + (i & 15))) * 512;
  }
  if (i < 1920L){
    int it = (int)(i >> 7), b = (int)(i & 127);
    tab_mgd[i] = ((long)(b * 31 + 30 - it)) * 512;
  }
  if (i < 1024L)  zb[i] = 0.f;
  if (i < 128L){ sl[i] = 0.f; ent[i] = 0.f; }
}

__global__ __launch_bounds__(256) void noise_u_k(float* __restrict__ u, uint32_t k0, uint32_t k1){
  uint32_t e = blockIdx.x * 256u + threadIdx.x; // < 1048576
  uint32_t b = e >> 13, rem = e & 8191u, n = rem >> 9, ee = rem & 511u;
  float nr = jax_normal(k0, k1, e);
  long off = ((long)(b * 31u + n)) * 512 + ee;
  u[off] += 0.01f * nr;
}

__global__ __launch_bounds__(256) void build_d_k(float* __restrict__ dmat, const float* __restrict__ u){
  int e = blockIdx.x * 256 + threadIdx.x; // 65536
  int b = e >> 9, ee = e & 511;
  long off = ((long)(b * 31 + 30)) * 512 + ee;
  dmat[off] = u[off];
}

// softmax stats + entropy + gumbel-argmax + mask + active update + next tables + b3 preset
__global__ __launch_bounds__(256) void sample_k(float* __restrict__ logits, int* __restrict__ active,
    int* __restrict__ actions, float* __restrict__ lp, float* __restrict__ ent,
    int it, int A, uint32_t k0, uint32_t k1, float log_opt,
    long* __restrict__ tab_loop, int* __restrict__ scat_loop, long* __restrict__ tab_pair,
    const float* __restrict__ pol_b3)
{
  int b = blockIdx.x, tid = threadIdx.x;
  int lane = tid & 63, wid = tid >> 6;
  float* Lg = logits + (long)b * 900;
  __shared__ float rmax[4], rS[4], rT[4], rG[4];
  __shared__ int rGi[4];
  __shared__ int ss0, ss1;

  // pass 1: max
  float v = -3.4e38f;
  for (int j = tid; j < 900; j += 256) v = fmaxf(v, Lg[j]);
#pragma unroll
  for (int m = 32; m; m >>= 1) v = fmaxf(v, __shfl_xor(v, m));
  if (lane == 0) rmax[wid] = v;
  __syncthreads();
  float mx = fmaxf(fmaxf(rmax[0], rmax[1]), fmaxf(rmax[2], rmax[3]));

  // pass 2: S = sum exp(l-m); T = sum e*(l-m) over unmasked
  float s = 0.f, t = 0.f;
  for (int j = tid; j < 900; j += 256){
    float l = Lg[j];
    float d = l - mx;
    float e = expf(d);
    s += e;
    if (l > MASKV) t = fmaf(e, d, t);
  }
#pragma unroll
  for (int m = 32; m; m >>= 1){ s += __shfl_xor(s, m); t += __shfl_xor(t, m); }
  if (lane == 0){ rS[wid] = s; rT[wid] = t; }

  // pass 3: gumbel argmax (earliest index wins on ties)
  float bv = -3.4e38f; int bi = 0;
  for (int j = tid; j < 900; j += 256){
    float g = jax_gumbel(k0, k1, (uint32_t)(b * 900 + j));
    float val = Lg[j] + g;
    if (val > bv){ bv = val; bi = j; }
  }
#pragma unroll
  for (int m = 32; m; m >>= 1){
    float ov = __shfl_xor(bv, m); int oi = __shfl_xor(bi, m);
    if (ov > bv || (ov == bv && oi < bi)){ bv = ov; bi = oi; }
  }
  if (lane == 0){ rG[wid] = bv; rGi[wid] = bi; }
  __syncthreads();

  if (tid == 0){
    float S = (rS[0] + rS[1]) + (rS[2] + rS[3]);
    float T = (rT[0] + rT[1]) + (rT[2] + rT[3]);
    ent[b] += -(T / S - logf(S)) / log_opt;
    float gb = rG[0]; int gi = rGi[0];
    for (int w = 1; w < 4; w++){
      if (rG[w] > gb || (rG[w] == gb && rGi[w] < gi)){ gb = rG[w]; gi = rGi[w]; }
    }
    int sf = gi;
    int s0 = sf / 30, s1 = sf % 30;
    ss0 = s0; ss1 = s1;
    actions[(b * 15 + it) * 2] = s0;
    actions[(b * 15 + it) * 2 + 1] = s1;
    lp[b * 15 + it] = Lg[sf] - mx - logf(S);
    tab_pair[b * 2]     = ((long)(b * 31 + s0)) * 512;
    tab_pair[b * 2 + 1] = ((long)(b * 31 + s1)) * 512;
  }
  __syncthreads();
  int s0 = ss0, s1 = ss1;
  if (tid < 30){
    Lg[s0 * 30 + tid] = MASKV;
    Lg[s1 * 30 + tid] = MASKV;
    Lg[tid * 30 + s0] = MASKV;
    Lg[tid * 30 + s1] = MASKV;
  }
  if (tid == 0){
    float b3v = pol_b3[0];
    int buf[16]; int c = 0;
    for (int k = 0; k < A; k++){
      int a = active[b * 16 + k];
      if (a != s0 && a != s1) buf[c++] = a;
    }
    int nt2 = 16 + it;
    buf[c++] = nt2;
    for (int k = 0; k < c; k++) active[b * 16 + k] = buf[k];
    int na2 = c - 1;
    for (int j = 0; j < na2; j++){
      int q = buf[j];
      int r1 = j * 128 + b;
      tab_loop[r1 * 2]     = ((long)(b * 31 + nt2)) * 1024;
      tab_loop[r1 * 2 + 1] = ((long)(b * 31 + q)) * 1024 + 512;
      int sc1 = b * 900 + nt2 * 30 + q;
      scat_loop[r1] = sc1;
      logits[sc1] = b3v;
      int r2 = (na2 + j) * 128 + b;
      tab_loop[r2 * 2]     = ((long)(b * 31 + q)) * 1024;
      tab_loop[r2 * 2 + 1] = ((long)(b * 31 + nt2)) * 1024 + 512;
      int sc2 = b * 900 + q * 30 + nt2;
      scat_loop[r2] = sc2;
      logits[sc2] = b3v;
    }
  }
}

__global__ __launch_bounds__(256) void finalize_k(const float* __restrict__ rew,
    const float* __restrict__ lp, const float* __restrict__ sl, const float* __restrict__ ent,
    float* __restrict__ out_sl, float* __restrict__ out_ent, float* __restrict__ out_reinf)
{
  __shared__ float red[256];
  int tid = threadIdx.x;
  float s = 0.f;
  for (int i = tid; i < 1920; i += 256) s += rew[i];
  red[tid] = s; __syncthreads();
  for (int st = 128; st > 0; st >>= 1){ if (tid < st) red[tid] += red[tid + st]; __syncthreads(); }
  float mean = red[0] / 1920.0f; __syncthreads();
  float v = 0.f;
  for (int i = tid; i < 1920; i += 256){ float x = rew[i] - mean; v = fmaf(x, x, v); }
  red[tid] = v; __syncthreads();
  for (int st = 128; st > 0; st >>= 1){ if (tid < st) red[tid] += red[tid + st]; __syncthreads(); }
  float denom = sqrtf(red[0] / 1919.0f) + 1e-20f;
  if (tid < 128){
    out_sl[tid] = sl[tid] / 15.0f;
    out_ent[tid] = ent[tid] / 15.0f;
    float r = 0.f;
    for (int k = 0; k < 15; k++){
      float rn = (rew[tid * 15 + k] - mean) / denom;
      r = fmaf(lp[tid * 15 + k], rn, r);
    }
    out_reinf[tid] = r;
  }
}

// ---------------- host ----------------
extern "C" void kernel_launch(void* const* d_in, const int* in_sizes, int n_in,
                              void* d_out, int out_size, void* d_ws, size_t ws_size,
                              hipStream_t stream)
{
  const float* x        = (const float*)d_in[0];
  const float* lift_w   = (const float*)d_in[1];
  const float* lift_b   = (const float*)d_in[2];
  const float* unlift_w = (const float*)d_in[3];
  const float* unlift_b = (const float*)d_in[4];
  const float* enc_w1   = (const float*)d_in[5];
  const float* enc_b1   = (const float*)d_in[6];
  const float* enc_w2   = (const float*)d_in[7];
  const float* enc_b2   = (const float*)d_in[8];
  const float* enc_w3   = (const float*)d_in[9];
  const float* enc_b3   = (const float*)d_in[10];
  const float* dec_w1   = (const float*)d_in[11];
  const float* dec_b1   = (const float*)d_in[12];
  const float* dec_w2   = (const float*)d_in[13];
  const float* dec_b2   = (const float*)d_in[14];
  const float* dec_w3   = (const float*)d_in[15];
  const float* dec_b3   = (const float*)d_in[16];
  const float* clf_w1   = (const float*)d_in[17];
  const float* clf_b1   = (const float*)d_in[18];
  const float* clf_w2   = (const float*)d_in[19];
  const float* clf_b2   = (const float*)d_in[20];
  const float* clf_w3   = (const float*)d_in[21];
  const float* clf_b3   = (const float*)d_in[22];
  const float* pol_w1   = (const float*)d_in[23];
  const float* pol_b1   = (const float*)d_in[24];
  const float* pol_w2   = (const float*)d_in[25];
  const float* pol_b2   = (const float*)d_in[26];
  const float* pol_w3   = (const float*)d_in[27];
  const float* pol_b3   = (const float*)d_in[28];

  float* out = (float*)d_out;
  const long U_OFF     = 2097152;
  const long D_OFF     = 4128768;
  const long SL_OFF    = 6160384;
  const long ENT_OFF   = 6160512;
  const long CLF_OFF   = 6160640;
  const long LBL_OFF   = 6168576;
  const long REINF_OFF = 6172544;
  float* recon = out;
  float* u     = out + U_OFF;
  float* dmat  = out + D_OFF;

  char* wsb = (char*)d_ws;
  size_t wo = 0;
  auto alloc = [&](size_t bytes) -> void* {
    void* p = (void*)(wsb + wo);
    wo = (wo + bytes + 255) & ~(size_t)255;
    return p;
  };
  float* logits    = (float*)alloc(115200 * 4);
  float* Y         = (float*)alloc((size_t)3968 * 1024 * 4); // dead after fwd -> overlays:
  float* h1clf     = Y;                  // tail clf hidden1 (3968x512)
  float* pbuf      = Y + 2031616;        // dec output 1920x1024, then clf h2
  float* h2clf     = Y + 2031616;
  float* W1cat     = (float*)alloc((size_t)524288 * 4);
  float* zb        = (float*)alloc(1024 * 4);
  float* h1        = (float*)alloc((size_t)2048 * 512 * 4);
  float* h2        = (float*)alloc((size_t)2048 * 512 * 4);
  float* z_all     = (float*)alloc((size_t)15 * 65536 * 4);
  float* sl        = (float*)alloc(128 * 4);
  float* ent       = (float*)alloc(128 * 4);
  float* lp        = (float*)alloc(1920 * 4);
  float* rew       = (float*)alloc(1920 * 4);
  int*   active    = (int*)alloc(2048 * 4);
  int*   actions   = (int*)alloc(3840 * 4);
  long*  tab_init  = (long*)alloc((size_t)30720 * 2 * 8);
  int*   scat_init = (int*)alloc(30720 * 4);
  long*  tab_loop  = (long*)alloc((size_t)3584 * 2 * 8);
  int*   scat_loop = (int*)alloc(3584 * 4);
  long*  tab_pair  = (long*)alloc(256 * 8);
  long*  tab_mgd   = (long*)alloc(1920 * 8);   // contiguous with tab_tok16 -> 3968-row clf table
  long*  tab_tok16 = (long*)alloc(2048 * 8);
  int*   scat_clf  = (int*)alloc(3968 * 4);
  long*  tab_clf   = tab_mgd;
  (void)ws_size; (void)in_sizes; (void)n_in; (void)out_size;

  uint32_t k7a, k7b, ck0[15], ck1[15], mk0[15], mk1[15];
  { uint32_t a = 0, b = 7; tf2x32(0u, 42u, a, b); k7a = a; k7b = b; }
  for (int it = 0; it < 15; it++){
    { uint32_t a = 0, b = (uint32_t)(100 + it); tf2x32(0u, 42u, a, b); ck0[it] = a; ck1[it] = b; }
    { uint32_t a = 0, b = (uint32_t)(1000 + it); tf2x32(0u, 42u, a, b); mk0[it] = a; mk1[it] = b; }
  }

  auto gemm = [&](int act, const float* A, int lda, const long* atab, int anblk,
                  const float* W, const float* bs, float* C, int rows, int K, int Nn,
                  long cb, int crd, long cos, long cis){
    dim3 g(Nn / 64, rows / 64);
    if (act) gemm_k<1><<<g, 256, 0, stream>>>(A, lda, atab, anblk, W, bs, C, K, Nn, cb, crd, cos, cis);
    else     gemm_k<0><<<g, 256, 0, stream>>>(A, lda, atab, anblk, W, bs, C, K, Nn, cb, crd, cos, cis);
  };

  // ---- init ----
  init_k<<<2048, 256, 0, stream>>>(out + LBL_OFF, logits, sl, ent, active, zb,
                                   W1cat, pol_w1, pol_b3, tab_init, scat_init, tab_tok16,
                                   tab_mgd, scat_clf, CLF_OFF);

  // ---- lift + noise ----
  gemm(0, x, 1024, nullptr, 0, lift_w, lift_b, u, 2048, 1024, 512, 0, 16, 15872, 512);
  noise_u_k<<<4096, 256, 0, stream>>>(u, k7a, k7b);

  // ---- Y init for tokens 0..15 ----
  gemm(0, u, 0, tab_tok16, 1, W1cat, zb, Y, 2048, 512, 1024, 0, 16, 31744, 1024);

  // ---- initial policy logits (round-4 best: 256x128 tile, 8x8, 512 threads) ----
  { dim3 g(4, 120);
    gemm128f_k<<<g, 512, 0, stream>>>(Y, tab_init, pol_b1, pol_w2, pol_b2, pol_w3,
                                      scat_init, logits); }

  // ---- forward merge loop (per-layer matvecs, max fill) ----
  for (int it = 0; it < 15; it++){
    int A = 16 - it;
    if (it > 0){
      int rows = 256 * (15 - it);
      dim3 g(8, rows / 64);
      gemm64f_k<<<g, 256, 0, stream>>>(Y, tab_loop, pol_b1, pol_w2, pol_b2, pol_w3,
                                       scat_loop, logits);
    }
    float log_opt = (float)log((double)(A * (A - 1)));
    sample_k<<<128, 256, 0, stream>>>(logits, active, actions, lp, ent, it, A,
                                      ck0[it], ck1[it], log_opt,
                                      tab_loop, scat_loop, tab_pair, pol_b3);
    { dim3 g(2, 128);
      pairmv_k<<<g, 256, 0, stream>>>(u, tab_pair, enc_w1, enc_b1, h1); }
    { dim3 g(2, 128);
      mvrelu_k<<<g, 256, 0, stream>>>(h1, 512, enc_w2, enc_b2, h2); }
    { dim3 g(2, 128);
      lay3z_k<<<g, 256, 0, stream>>>(h2, enc_w3, enc_b3, z_all, u, it, mk0[it], mk1[it]); }
    if (it < 14){
      dim3 g(4, 128);
      yrow_k<<<g, 256, 0, stream>>>(u, W1cat, Y, it);
    }
  }

  // ---- deferred batched dec over all 15 steps (1920 rows), then osl ----
  gemm(1, z_all, 512, nullptr, 0, dec_w1, dec_b1, h1, 1920, 512, 512, 0, 1, 512, 0);
  gemm(1, h1, 512, nullptr, 0, dec_w2, dec_b2, h2, 1920, 512, 512, 0, 1, 512, 0);
  gemm(0, h2, 512, nullptr, 0, dec_w3, dec_b3, pbuf, 1920, 512, 1024, 0, 1, 1024, 0);
  oslb_k<<<1920, 256, 0, stream>>>(pbuf, u, actions, sl, rew);

  // ---- d init (only token 30 active) ----
  build_d_k<<<256, 256, 0, stream>>>(dmat, u);

  // ---- reverse unmerge loop: 3 wide layers per step ----
  for (int it = 0; it < 15; it++){
    int tok = 30 - it;
    { dim3 g(2, 128);
      mvrelu_k<<<g, 256, 0, stream>>>(dmat + (long)tok * 512, 15872, dec_w1, dec_b1, h1); }
    { dim3 g(2, 128);
      mvrelu_k<<<g, 256, 0, stream>>>(h1, 512, dec_w2, dec_b2, h2); }
    { dim3 g(4, 128);
      rev3_k<<<g, 256, 0, stream>>>(h2, dec_w3, dec_b3, dmat, actions, it); }
  }

  // ---- combined clf over mgd rows (1920) + final d[:, :16] rows (2048) ----
  gemm(1, dmat, 0, tab_clf, 1, clf_w1, clf_b1, h1clf, 3968, 512, 512, 0, 1, 512, 0);
  gemm(1, h1clf, 512, nullptr, 0, clf_w2, clf_b2, h2clf, 3968, 512, 512, 0, 1, 512, 0);
  rowdot2_k<<<992, 256, 0, stream>>>(h2clf, 512, clf_w3, clf_b3, 512, out, scat_clf);

  // ---- recon = d[:, :16] @ unlift_w + unlift_b ----
  gemm(0, dmat, 0, tab_tok16, 1, unlift_w, unlift_b, recon, 2048, 512, 1024,
       0, 16, 16384, 1024);

  // ---- reward normalization, reinf, per-batch losses ----
  finalize_k<<<1, 256, 0, stream>>>(rew, lp, sl, ent,
                                    out + SL_OFF, out + ENT_OFF, out + REINF_OFF);
}